// Round 4
// baseline (60.239 us; speedup 1.0000x reference)
//
#include <hip/hip_runtime.h>

typedef __attribute__((ext_vector_type(8))) short short8;
typedef __attribute__((ext_vector_type(4))) float f32x4;

__device__ __forceinline__ unsigned short f2bf(float f) {
    union { float f; unsigned int u; } v; v.f = f;
    unsigned int u = v.u;
    unsigned int r = u + 0x7FFFu + ((u >> 16) & 1u);
    return (unsigned short)(r >> 16);
}

// Kernel A: Wmat[e][c] = sum_d proj_w[e][d] * v_w[d][c], bf16 row-major [e][c].
// IDENTICAL to R3 (anchor for the ablation equation).
__global__ __launch_bounds__(1024) void wmat_kernel(
    const float* __restrict__ v_w, const float* __restrict__ proj_w,
    unsigned short* __restrict__ Wm)
{
    __shared__ float red[4][256];
    const int e  = blockIdx.x;
    const int c  = threadIdx.x & 255;
    const int dq = threadIdx.x >> 8;   // 0..3

    const float* pw = proj_w + e * 256 + dq * 64;   // wave-uniform -> s_loads
    const float* vv = v_w + (dq * 64) * 256 + c;

    float acc = 0.f;
#pragma unroll 8
    for (int d = 0; d < 64; ++d)
        acc = fmaf(pw[d], vv[d * 256], acc);

    red[dq][c] = acc;
    __syncthreads();
    if (threadIdx.x < 256) {
        float s = red[0][c] + red[1][c] + red[2][c] + red[3][c];
        Wm[e * 256 + c] = f2bf(s);
    }
}

// Kernel B: IDENTICAL to R3. Launched TWICE this round (idempotent) so that
// dur_us = wmat + 2*fused + c  vs R3's  wmat + fused + c = 35.66 us
// => fused = X - 35.66 us. Pure measurement round.
__global__ __launch_bounds__(256, 4) void fused_kernel(
    const float* __restrict__ x, const unsigned short* __restrict__ Wm,
    const float* __restrict__ proj_b, float* __restrict__ out)
{
    const int idx   = ((blockIdx.x & 7) << 7) | (blockIdx.x >> 3);  // 1024 = 8*128, bijective
    const int b     = idx >> 7;
    const int h     = (idx >> 1) & 63;
    const int wbase = (idx & 1) * 32;
    const int t     = threadIdx.x;

    __shared__ unsigned short ylds[32 * 256];   // 16 KB, bf16, XOR-swizzled

    const float A1  = (float)(1.0 / 10.71828182845904523536);                 // 1/(e+8)
    const float A0D = (float)(2.71828182845904523536 / 10.71828182845904523536) - A1; // A0-A1

    // ---------------- blur phase (4-pixel strip per thread) ----------------
    {
        const int wl0 = (t >> 5) * 4;     // local strip start in [0,32)
        const int c0  = (t & 31) * 8;     // 8-channel chunk
        const int gw0 = wbase + wl0;      // global pixel of strip start

        const f32x4 z = {0.f, 0.f, 0.f, 0.f};
        f32x4 acc[4][2];
#pragma unroll
        for (int i = 0; i < 4; ++i) { acc[i][0] = z; acc[i][1] = z; }

        for (int r = h - 1; r <= h + 1; ++r) {
            if (r < 0 || r >= 64) continue;
            const bool top = (r == h - 1);
            const float* xr = x + (((size_t)b * 64 + r) * 64) * 256 + c0;

            f32x4 pm0, pm1, pc0, pc1;
            if (gw0 == 0) { pm0 = z; pm1 = z; }
            else {
                pm0 = *(const f32x4*)(xr + (gw0 - 1) * 256);
                pm1 = *(const f32x4*)(xr + (gw0 - 1) * 256 + 4);
            }
            pc0 = *(const f32x4*)(xr + gw0 * 256);
            pc1 = *(const f32x4*)(xr + gw0 * 256 + 4);

#pragma unroll
            for (int i = 0; i < 4; ++i) {
                const int gwn = gw0 + i + 1;
                f32x4 pn0 = z, pn1 = z;
                if (gwn < 64) {
                    pn0 = *(const f32x4*)(xr + gwn * 256);
                    pn1 = *(const f32x4*)(xr + gwn * 256 + 4);
                }
                f32x4 s0 = pm0 + pc0 + pn0;
                f32x4 s1 = pm1 + pc1 + pn1;
                acc[i][0] += A1 * s0;
                acc[i][1] += A1 * s1;
                if (top) {   // tap k=0 extra weight on x[h-1][w-1]
                    acc[i][0] += A0D * pm0;
                    acc[i][1] += A0D * pm1;
                }
                pm0 = pc0; pm1 = pc1; pc0 = pn0; pc1 = pn1;
            }
        }

        // pack to bf16, write swizzled: byte ^= ((w&7)<<4)
#pragma unroll
        for (int i = 0; i < 4; ++i) {
            const int w = wl0 + i;        // local row in [0,32)
            union { short8 v; unsigned short u[8]; } pk;
#pragma unroll
            for (int j = 0; j < 4; ++j) {
                pk.u[j]     = f2bf(acc[i][0][j]);
                pk.u[4 + j] = f2bf(acc[i][1][j]);
            }
            unsigned baddr = ((unsigned)w * 512u + (unsigned)c0 * 2u) ^ (((unsigned)(w & 7)) << 4);
            *reinterpret_cast<short8*>(reinterpret_cast<char*>(ylds) + baddr) = pk.v;
        }
    }
    __syncthreads();

    // ---------------- GEMM phase: out[32,256] = y @ Wm^T + b ----------------
    {
        const int wave = t >> 6;          // 0..3 -> N quarter [wave*64, +64)
        const int lane = t & 63;
        const int lrow = lane & 15;
        const int lkg  = lane >> 4;       // 0..3 k-group
        const int n_base = wave * 64;

        const f32x4 z = {0.f, 0.f, 0.f, 0.f};
        f32x4 acc2[2][4];                 // [mi(pixel block)][ni(e block)]
#pragma unroll
        for (int mi = 0; mi < 2; ++mi)
#pragma unroll
            for (int ni = 0; ni < 4; ++ni) acc2[mi][ni] = z;

        for (int k0 = 0; k0 < 256; k0 += 32) {
            const int koff = k0 + lkg * 8;
            short8 a[2], bf[4];
#pragma unroll
            for (int mi = 0; mi < 2; ++mi) {
                const int row = mi * 16 + lrow;
                unsigned baddr = ((unsigned)row * 512u + (unsigned)koff * 2u) ^ (((unsigned)(row & 7)) << 4);
                a[mi] = *reinterpret_cast<const short8*>(reinterpret_cast<const char*>(ylds) + baddr);
            }
#pragma unroll
            for (int ni = 0; ni < 4; ++ni) {
                const int e = n_base + ni * 16 + lrow;
                bf[ni] = *reinterpret_cast<const short8*>(Wm + e * 256 + koff);
            }
            // operand-swapped: D = W-frag (A) * y-frag (B) -> D[e][pixel];
            // lane holds e = ni*16 + lkg*4 + 0..3 (consecutive) for pixel mi*16+lrow
#pragma unroll
            for (int mi = 0; mi < 2; ++mi)
#pragma unroll
                for (int ni = 0; ni < 4; ++ni)
                    acc2[mi][ni] = __builtin_amdgcn_mfma_f32_16x16x32_bf16(bf[ni], a[mi], acc2[mi][ni], 0, 0, 0);
        }

        // epilogue: vector bias + f32x4 nontemporal stores
        const size_t outbase = (((size_t)b * 64 + h) * 64 + wbase) * 256;
        f32x4 bias4[4];
#pragma unroll
        for (int ni = 0; ni < 4; ++ni)
            bias4[ni] = *reinterpret_cast<const f32x4*>(proj_b + n_base + ni * 16 + lkg * 4);

#pragma unroll
        for (int mi = 0; mi < 2; ++mi) {
            const int pixel = mi * 16 + lrow;   // local pixel in [0,32)
            float* orow = out + outbase + (size_t)pixel * 256 + n_base + lkg * 4;
#pragma unroll
            for (int ni = 0; ni < 4; ++ni) {
                f32x4 v = acc2[mi][ni] + bias4[ni];
                __builtin_nontemporal_store(v, reinterpret_cast<f32x4*>(orow + ni * 16));
            }
        }
    }
}

extern "C" void kernel_launch(void* const* d_in, const int* in_sizes, int n_in,
                              void* d_out, int out_size, void* d_ws, size_t ws_size,
                              hipStream_t stream) {
    const float* x      = (const float*)d_in[0];
    const float* v_w    = (const float*)d_in[1];
    const float* proj_w = (const float*)d_in[2];
    const float* proj_b = (const float*)d_in[3];
    float* out = (float*)d_out;
    unsigned short* Wm = (unsigned short*)d_ws;   // 256*256 bf16 = 128 KB

    wmat_kernel<<<256, 1024, 0, stream>>>(v_w, proj_w, Wm);
    // ABLATION: fused launched twice (idempotent, same output).
    // dur = wmat + 2*fused + overhead; R3 anchor = wmat + fused + overhead = 35.66us.
    fused_kernel<<<1024, 256, 0, stream>>>(x, Wm, proj_b, out);
    fused_kernel<<<1024, 256, 0, stream>>>(x, Wm, proj_b, out);
}

// Round 5
// 49.813 us; speedup vs baseline: 1.2093x; 1.2093x over previous
//
#include <hip/hip_runtime.h>

typedef __attribute__((ext_vector_type(8))) short short8;
typedef __attribute__((ext_vector_type(4))) float f32x4;

__device__ __forceinline__ unsigned short f2bf(float f) {
    union { float f; unsigned int u; } v; v.f = f;
    unsigned int u = v.u;
    unsigned int r = u + 0x7FFFu + ((u >> 16) & 1u);
    return (unsigned short)(r >> 16);
}

// Kernel 1 (combo): blocks 0..255 compute Wm rows (hidden under blur blocks);
// blocks 256..1279 compute the 3x3 weighted blur y = blur(x) in bf16 to d_ws.
// No LDS, no barriers, small VGPR -> high occupancy; all x re-reads are L2/L3 hits.
__global__ __launch_bounds__(256) void combo_kernel(
    const float* __restrict__ x, const float* __restrict__ v_w,
    const float* __restrict__ proj_w, unsigned short* __restrict__ Wm,
    unsigned short* __restrict__ y)
{
    if (blockIdx.x < 256) {
        // ---- wmat: Wm[e][c] = sum_d proj_w[e][d] * v_w[d][c], bf16 ----
        const int e = blockIdx.x;
        const int c = threadIdx.x;
        const float* pw = proj_w + e * 256;     // block-uniform -> s_loads
        const float* vv = v_w + c;
        float acc = 0.f;
#pragma unroll 16
        for (int d = 0; d < 256; ++d)
            acc = fmaf(pw[d], vv[d * 256], acc);
        Wm[e * 256 + c] = f2bf(acc);
        return;
    }

    // ---- blur: half-row (32 px x 256 ch), 4-px strip per thread ----
    const int idx   = blockIdx.x - 256;         // 0..1023
    const int b     = idx >> 7;
    const int h     = (idx >> 1) & 63;
    const int wbase = (idx & 1) * 32;
    const int t     = threadIdx.x;

    const float A1  = (float)(1.0 / 10.71828182845904523536);                 // 1/(e+8)
    const float A0D = (float)(2.71828182845904523536 / 10.71828182845904523536) - A1; // A0-A1

    const int wl0 = (t >> 5) * 4;     // local strip start in [0,32)
    const int c0  = (t & 31) * 8;     // 8-channel chunk
    const int gw0 = wbase + wl0;      // global pixel x of strip start

    const f32x4 z = {0.f, 0.f, 0.f, 0.f};
    f32x4 acc[4][2];
#pragma unroll
    for (int i = 0; i < 4; ++i) { acc[i][0] = z; acc[i][1] = z; }

    for (int r = h - 1; r <= h + 1; ++r) {
        if (r < 0 || r >= 64) continue;
        const bool top = (r == h - 1);
        const float* xr = x + (((size_t)b * 64 + r) * 64) * 256 + c0;

        f32x4 pm0, pm1, pc0, pc1;
        if (gw0 == 0) { pm0 = z; pm1 = z; }
        else {
            pm0 = *(const f32x4*)(xr + (gw0 - 1) * 256);
            pm1 = *(const f32x4*)(xr + (gw0 - 1) * 256 + 4);
        }
        pc0 = *(const f32x4*)(xr + gw0 * 256);
        pc1 = *(const f32x4*)(xr + gw0 * 256 + 4);

#pragma unroll
        for (int i = 0; i < 4; ++i) {
            const int gwn = gw0 + i + 1;
            f32x4 pn0 = z, pn1 = z;
            if (gwn < 64) {
                pn0 = *(const f32x4*)(xr + gwn * 256);
                pn1 = *(const f32x4*)(xr + gwn * 256 + 4);
            }
            f32x4 s0 = pm0 + pc0 + pn0;
            f32x4 s1 = pm1 + pc1 + pn1;
            acc[i][0] += A1 * s0;
            acc[i][1] += A1 * s1;
            if (top) {   // tap k=0 extra weight on x[h-1][w-1]
                acc[i][0] += A0D * pm0;
                acc[i][1] += A0D * pm1;
            }
            pm0 = pc0; pm1 = pc1; pc0 = pn0; pc1 = pn1;
        }
    }

    // pack to bf16, store linear: y[p][c], p = idx*32 + wl0 + i
#pragma unroll
    for (int i = 0; i < 4; ++i) {
        union { short8 v; unsigned short u[8]; } pk;
#pragma unroll
        for (int j = 0; j < 4; ++j) {
            pk.u[j]     = f2bf(acc[i][0][j]);
            pk.u[4 + j] = f2bf(acc[i][1][j]);
        }
        *reinterpret_cast<short8*>(y + ((size_t)idx * 32 + wl0 + i) * 256 + c0) = pk.v;
    }
}

// Kernel 2: out[32768,256] = y @ Wm^T + proj_b.
// BM=64, BN=256 (full), 512 blocks x 512 threads (8 waves = 2M x 4N).
// Operands direct from global (y rows + 128KB Wm, both L2/L3-resident);
// no LDS, no barriers. Operand-swapped MFMA -> lane holds 4 consecutive e
// -> f32x4 nontemporal stores (R3-verified fragment math).
__global__ __launch_bounds__(512, 4) void gemm_kernel(
    const unsigned short* __restrict__ y, const unsigned short* __restrict__ Wm,
    const float* __restrict__ proj_b, float* __restrict__ out)
{
    const int pbase = blockIdx.x * 64;
    const int t     = threadIdx.x;
    const int wave  = t >> 6;
    const int lane  = t & 63;
    const int wm    = wave >> 2;        // 0..1 -> M-half (32 px)
    const int wn    = wave & 3;         // 0..3 -> N-quarter (64 e)
    const int lrow  = lane & 15;
    const int lkg   = lane >> 4;        // 0..3 k-group
    const int n_base = wn * 64;
    const int prow0  = pbase + wm * 32;

    const f32x4 z = {0.f, 0.f, 0.f, 0.f};
    f32x4 acc[2][4];
#pragma unroll
    for (int mi = 0; mi < 2; ++mi)
#pragma unroll
        for (int ni = 0; ni < 4; ++ni) acc[mi][ni] = z;

    for (int k0 = 0; k0 < 256; k0 += 32) {
        const int koff = k0 + lkg * 8;
        short8 a[2], bf[4];
#pragma unroll
        for (int mi = 0; mi < 2; ++mi)
            a[mi] = *reinterpret_cast<const short8*>(
                y + (size_t)(prow0 + mi * 16 + lrow) * 256 + koff);
#pragma unroll
        for (int ni = 0; ni < 4; ++ni)
            bf[ni] = *reinterpret_cast<const short8*>(
                Wm + (n_base + ni * 16 + lrow) * 256 + koff);
        // D = Wm-frag (A) * y-frag (B): lane holds e = ni*16+lkg*4+0..3, px = mi*16+lrow
#pragma unroll
        for (int mi = 0; mi < 2; ++mi)
#pragma unroll
            for (int ni = 0; ni < 4; ++ni)
                acc[mi][ni] = __builtin_amdgcn_mfma_f32_16x16x32_bf16(bf[ni], a[mi], acc[mi][ni], 0, 0, 0);
    }

    // epilogue: vector bias + f32x4 nontemporal stores
    f32x4 bias4[4];
#pragma unroll
    for (int ni = 0; ni < 4; ++ni)
        bias4[ni] = *reinterpret_cast<const f32x4*>(proj_b + n_base + ni * 16 + lkg * 4);

#pragma unroll
    for (int mi = 0; mi < 2; ++mi) {
        const int pixel = prow0 + mi * 16 + lrow;
        float* orow = out + (size_t)pixel * 256 + n_base + lkg * 4;
#pragma unroll
        for (int ni = 0; ni < 4; ++ni) {
            f32x4 v = acc[mi][ni] + bias4[ni];
            __builtin_nontemporal_store(v, reinterpret_cast<f32x4*>(orow + ni * 16));
        }
    }
}

extern "C" void kernel_launch(void* const* d_in, const int* in_sizes, int n_in,
                              void* d_out, int out_size, void* d_ws, size_t ws_size,
                              hipStream_t stream) {
    const float* x      = (const float*)d_in[0];
    const float* v_w    = (const float*)d_in[1];
    const float* proj_w = (const float*)d_in[2];
    const float* proj_b = (const float*)d_in[3];
    float* out = (float*)d_out;

    unsigned short* Wm = (unsigned short*)d_ws;                  // 128 KB
    unsigned short* y  = (unsigned short*)((char*)d_ws + 131072); // 16.8 MB bf16

    combo_kernel<<<1280, 256, 0, stream>>>(x, v_w, proj_w, Wm, y);
    gemm_kernel<<<512, 512, 0, stream>>>(y, Wm, proj_b, out);
}

// Round 6
// 38.270 us; speedup vs baseline: 1.5740x; 1.3016x over previous
//
#include <hip/hip_runtime.h>

typedef __attribute__((ext_vector_type(8))) short short8;
typedef __attribute__((ext_vector_type(4))) short short4v;
typedef __attribute__((ext_vector_type(4))) float f32x4;

__device__ __forceinline__ unsigned short f2bf(float f) {
    union { float f; unsigned int u; } v; v.f = f;
    unsigned int u = v.u;
    unsigned int r = u + 0x7FFFu + ((u >> 16) & 1u);
    return (unsigned short)(r >> 16);
}

// Kernel A: W = proj_w @ v_w, bf16, stored PRE-SWIZZLED for the GEMM:
// element W[e][c] with e=(wn*64+ni*16+lrow), c=(kk*32+lkg*8+c8), lane=lkg*16+lrow
// lands at idx = (((wn*8+kk)*4+ni)*64 + lane)*8 + c8  -> every GEMM B-load is a
// contiguous 1KB wave-load (lane*16B).
__global__ __launch_bounds__(1024) void wmat_kernel(
    const float* __restrict__ v_w, const float* __restrict__ proj_w,
    unsigned short* __restrict__ Wm)
{
    __shared__ float red[4][256];
    const int e  = blockIdx.x;
    const int c  = threadIdx.x & 255;
    const int dq = threadIdx.x >> 8;   // 0..3

    const float* pw = proj_w + e * 256 + dq * 64;   // wave-uniform -> s_loads
    const float* vv = v_w + (dq * 64) * 256 + c;

    float acc = 0.f;
#pragma unroll 8
    for (int d = 0; d < 64; ++d)
        acc = fmaf(pw[d], vv[d * 256], acc);

    red[dq][c] = acc;
    __syncthreads();
    if (threadIdx.x < 256) {
        float s = red[0][c] + red[1][c] + red[2][c] + red[3][c];
        const int wn = e >> 6, ni = (e >> 4) & 3, lrow = e & 15;
        const int kk = c >> 5, lkg = (c >> 3) & 3, c8 = c & 7;
        const int lane = lkg * 16 + lrow;
        const int idx = ((((wn * 8 + kk) * 4 + ni) * 64 + lane) * 8) + c8;
        Wm[idx] = f2bf(s);
    }
}

// Kernel B: one block per half-row (32 px x 256 ch), 512 threads (8 waves).
// Phase 1: 3x3 weighted blur -> y bf16 in XOR-swizzled LDS (f32x4-granular strips).
// Phase 2: wave = 16px x 64e tile; A-frag from LDS, B-frag = coalesced 1KB loads
// from pre-swizzled Wm; operand-swapped MFMA (R3-verified) -> f32x4 NT stores.
__global__ __launch_bounds__(512, 6) void fused_kernel(
    const float* __restrict__ x, const unsigned short* __restrict__ Wm,
    const float* __restrict__ proj_b, float* __restrict__ out)
{
    const int idx   = blockIdx.x;       // 0..1023
    const int b     = idx >> 7;
    const int h     = (idx >> 1) & 63;
    const int wbase = (idx & 1) * 32;
    const int t     = threadIdx.x;

    __shared__ unsigned short ylds[32 * 256];   // 16 KB

    const float A1  = (float)(1.0 / 10.71828182845904523536);                 // 1/(e+8)
    const float A0D = (float)(2.71828182845904523536 / 10.71828182845904523536) - A1; // A0-A1

    // ---------------- blur: 8 strips(4px) x 64 chunks(4ch) = 512 tasks ----------------
    {
        const int strip = t >> 6;         // 0..7
        const int c0    = (t & 63) * 4;   // 4-channel chunk
        const int px0   = strip * 4;      // local pixel in [0,32)
        const int gw0   = wbase + px0;    // global pixel

        const f32x4 z = {0.f, 0.f, 0.f, 0.f};
        f32x4 acc[4];
#pragma unroll
        for (int i = 0; i < 4; ++i) acc[i] = z;

        for (int r = h - 1; r <= h + 1; ++r) {
            if (r < 0 || r >= 64) continue;
            const bool top = (r == h - 1);
            const float* xr = x + (((size_t)b * 64 + r) * 64) * 256 + c0;

            f32x4 pm, pc;
            pm = (gw0 == 0) ? z : *(const f32x4*)(xr + (gw0 - 1) * 256);
            pc = *(const f32x4*)(xr + gw0 * 256);

#pragma unroll
            for (int i = 0; i < 4; ++i) {
                const int gwn = gw0 + i + 1;
                f32x4 pn = (gwn < 64) ? *(const f32x4*)(xr + gwn * 256) : z;
                acc[i] += A1 * (pm + pc + pn);
                if (top) acc[i] += A0D * pm;   // tap k=0 extra weight on x[h-1][w-1]
                pm = pc; pc = pn;
            }
        }

        // pack to bf16, write swizzled: byte ^= ((w&7)<<4)
#pragma unroll
        for (int i = 0; i < 4; ++i) {
            const int w = px0 + i;
            union { short4v v; unsigned short u[4]; } pk;
#pragma unroll
            for (int j = 0; j < 4; ++j) pk.u[j] = f2bf(acc[i][j]);
            unsigned baddr = ((unsigned)w * 512u + (unsigned)c0 * 2u) ^ (((unsigned)(w & 7)) << 4);
            *reinterpret_cast<short4v*>(reinterpret_cast<char*>(ylds) + baddr) = pk.v;
        }
    }
    __syncthreads();

    // ---------------- GEMM: out[32,256] = y @ W^T + b ----------------
    {
        const int wave = t >> 6;          // 0..7
        const int lane = t & 63;
        const int wm   = wave >> 2;       // 0..1 -> 16-px half
        const int wn   = wave & 3;        // 0..3 -> 64-e quarter
        const int lrow = lane & 15;
        const int lkg  = lane >> 4;       // 0..3

        const int row  = wm * 16 + lrow;  // local pixel this lane produces
        const unsigned abase = (unsigned)row * 512u;
        const unsigned aswz  = ((unsigned)(row & 7)) << 4;

        const unsigned short* wv = Wm + ((size_t)wn << 14) + (lane << 3); // wn*16384 + lane*8

        const f32x4 z = {0.f, 0.f, 0.f, 0.f};
        f32x4 acc2[4];
#pragma unroll
        for (int ni = 0; ni < 4; ++ni) acc2[ni] = z;

#pragma unroll
        for (int kk = 0; kk < 8; ++kk) {
            // A-frag: y[row][kk*32 + lkg*8 .. +8]  (byte off = kk*64 + lkg*16)
            const unsigned abyte = (abase + (unsigned)(kk * 64 + lkg * 16)) ^ aswz;
            short8 a = *reinterpret_cast<const short8*>(reinterpret_cast<const char*>(ylds) + abyte);
            const unsigned short* wk = wv + (kk << 11);   // kk*2048
#pragma unroll
            for (int ni = 0; ni < 4; ++ni) {
                short8 bf = *reinterpret_cast<const short8*>(wk + (ni << 9)); // ni*512
                acc2[ni] = __builtin_amdgcn_mfma_f32_16x16x32_bf16(bf, a, acc2[ni], 0, 0, 0);
            }
        }

        // epilogue: bias + f32x4 nontemporal stores
        // lane holds e = wn*64 + ni*16 + lkg*4 + 0..3 for pixel (idx*32 + row)
        float* orow = out + ((size_t)(idx * 32 + row)) * 256 + wn * 64 + lkg * 4;
#pragma unroll
        for (int ni = 0; ni < 4; ++ni) {
            f32x4 bias = *reinterpret_cast<const f32x4*>(proj_b + wn * 64 + ni * 16 + lkg * 4);
            f32x4 v = acc2[ni] + bias;
            __builtin_nontemporal_store(v, reinterpret_cast<f32x4*>(orow + ni * 16));
        }
    }
}

extern "C" void kernel_launch(void* const* d_in, const int* in_sizes, int n_in,
                              void* d_out, int out_size, void* d_ws, size_t ws_size,
                              hipStream_t stream) {
    const float* x      = (const float*)d_in[0];
    const float* v_w    = (const float*)d_in[1];
    const float* proj_w = (const float*)d_in[2];
    const float* proj_b = (const float*)d_in[3];
    float* out = (float*)d_out;
    unsigned short* Wm = (unsigned short*)d_ws;   // 65536 bf16 = 128 KB, swizzled

    wmat_kernel<<<256, 1024, 0, stream>>>(v_w, proj_w, Wm);
    fused_kernel<<<1024, 512, 0, stream>>>(x, Wm, proj_b, out);
}